// Round 7
// baseline (392.588 us; speedup 1.0000x reference)
//
#include <hip/hip_runtime.h>

// C3 partial conv: x[64,6,256,256] f32, W[16,6,5,5] f32 (sparse table), b[16].
// out[64,16,252,252] f32 = 1.7159*tanh((2/3)*(conv_valid + b)).
//
// Round 10: break the per-case weight-load serialization. r7(64% occ) ==
// r9(43% occ) == ~275us proved the wall is invariant: in the rolled switch,
// each case's 25 weight s_loads can't be prefetched across the unresolved
// branch -> ~50% dead time x 60 cases. Fix:
//  (a) switch now only routes a temp accumulator (2 adds/case) -- the 50-FMA
//      block is branch-free shared code, so weight addresses are known
//      BEFORE any branch;
//  (b) weights live in a 128B-aligned padded copy Wp[96][32] in d_ws (prep
//      kernel), loaded as 7x float4 VECTOR loads (vmcnt-tracked);
//  (c) manual 2-deep pipeline over a flat (c,o) schedule: pair p+1's loads
//      issue before pair p's FMA block -> latency hides under the FMAs.
// 2-row/thread, 19.2KB tile (register headroom for qA+qB+win+acc ~ 120).
// NO launch_bounds min-waves arg (hard VGPR clamp -> scratch, r2/r4).

#define E(o,c) (uint32_t)((((o)*6+(c))*32) | (((o)&7)<<16) | ((c)<<20))

// flat schedules, c-major (win reloads only at c boundaries: 6 per group)
__device__ __constant__ uint32_t SCHED0[26] = {
    E(0,0),E(4,0),E(5,0),E(6,0),
    E(0,1),E(1,1),E(5,1),E(6,1),E(7,1),
    E(0,2),E(1,2),E(2,2),E(6,2),E(7,2),
    E(1,3),E(2,3),E(3,3),E(6,3),E(7,3),
    E(2,4),E(3,4),E(4,4),E(7,4),
    E(3,5),E(4,5),E(5,5)};
__device__ __constant__ uint32_t SCHED1[34] = {
    E(9,0),E(10,0),E(11,0),E(12,0),E(14,0),E(15,0),
    E(10,1),E(11,1),E(12,1),E(13,1),E(15,1),
    E(8,2),E(11,2),E(13,2),E(14,2),E(15,2),
    E(8,3),E(9,3),E(12,3),E(14,3),E(15,3),
    E(8,4),E(9,4),E(10,4),E(12,4),E(13,4),E(15,4),
    E(8,5),E(9,5),E(10,5),E(11,5),E(13,5),E(14,5),E(15,5)};

__global__ void prep_weights(const float* __restrict__ W, float* __restrict__ Wp) {
    int i = blockIdx.x * 256 + threadIdx.x;   // 0..3071
    if (i < 16 * 6 * 32) {
        int oc = i >> 5, k = i & 31;
        Wp[i] = (k < 25) ? W[oc * 25 + k] : 0.0f;
    }
}

__device__ __forceinline__ void loadw(const float* __restrict__ p, float4 (&q)[7]) {
    const float4* p4 = reinterpret_cast<const float4*>(p);   // 128B-aligned
    #pragma unroll
    for (int i = 0; i < 7; ++i) q[i] = p4[i];
}

__device__ __forceinline__ void loadwin(const float* __restrict__ base, float (&win)[6][5]) {
    #pragma unroll
    for (int r = 0; r < 6; ++r)
        #pragma unroll
        for (int j = 0; j < 5; ++j)
            win[r][j] = base[r * 40 + j];   // one v-addr + immediate offsets
}

__device__ __forceinline__ void fma50(const float4 (&q)[7], const float (&win)[6][5],
                                      float& t0, float& t1) {
    t0 = win[0][0] * q[0].x;
    t1 = win[1][0] * q[0].x;
    #pragma unroll
    for (int m = 1; m < 25; ++m) {
        const int ky = m / 5, kx = m % 5;
        const int i = m >> 2, j = m & 3;
        float wv = (j == 0) ? q[i].x : (j == 1) ? q[i].y : (j == 2) ? q[i].z : q[i].w;
        t0 = fmaf(win[ky][kx],     wv, t0);
        t1 = fmaf(win[ky + 1][kx], wv, t1);
    }
}

template <int N>
__device__ __forceinline__ void run_group(const uint32_t* __restrict__ sched,
                                          const float* __restrict__ Wp,
                                          const float* __restrict__ ldsBase,  // &lds[0][row0][tx]
                                          float (&acc)[8][2]) {
    float4 qA[7], qB[7];
    float win[6][5];
    int ccur = -1;
    loadw(Wp + (sched[0] & 0xffffu), qA);           // prologue: pair 0 in flight
    #pragma unroll 1
    for (int p = 0; p < N; p += 2) {
        const uint32_t eA = sched[p];
        const uint32_t eB = sched[p + 1];
        const uint32_t eN = sched[(p + 2 < N) ? p + 2 : p];
        // ---- stage A: prefetch B, consume A ----
        loadw(Wp + (eB & 0xffffu), qB);
        int cA = (eA >> 20) & 7;
        if (cA != ccur) { ccur = cA; loadwin(ldsBase + cA * 800, win); }
        float t0, t1;
        fma50(qA, win, t0, t1);
        switch ((eA >> 16) & 15) {                   // 2 adds per case
            case 0: acc[0][0] += t0; acc[0][1] += t1; break;
            case 1: acc[1][0] += t0; acc[1][1] += t1; break;
            case 2: acc[2][0] += t0; acc[2][1] += t1; break;
            case 3: acc[3][0] += t0; acc[3][1] += t1; break;
            case 4: acc[4][0] += t0; acc[4][1] += t1; break;
            case 5: acc[5][0] += t0; acc[5][1] += t1; break;
            case 6: acc[6][0] += t0; acc[6][1] += t1; break;
            case 7: acc[7][0] += t0; acc[7][1] += t1; break;
            default: break;
        }
        // ---- stage B: prefetch next A, consume B ----
        loadw(Wp + (eN & 0xffffu), qA);
        int cB = (eB >> 20) & 7;
        if (cB != ccur) { ccur = cB; loadwin(ldsBase + cB * 800, win); }
        fma50(qB, win, t0, t1);
        switch ((eB >> 16) & 15) {
            case 0: acc[0][0] += t0; acc[0][1] += t1; break;
            case 1: acc[1][0] += t0; acc[1][1] += t1; break;
            case 2: acc[2][0] += t0; acc[2][1] += t1; break;
            case 3: acc[3][0] += t0; acc[3][1] += t1; break;
            case 4: acc[4][0] += t0; acc[4][1] += t1; break;
            case 5: acc[5][0] += t0; acc[5][1] += t1; break;
            case 6: acc[6][0] += t0; acc[6][1] += t1; break;
            case 7: acc[7][0] += t0; acc[7][1] += t1; break;
            default: break;
        }
    }
}

__global__ __launch_bounds__(256) void c3_partial_conv_kernel(
    const float* __restrict__ x,    // [64,6,256,256]
    const float* __restrict__ Wp,   // padded [96][32] in d_ws
    const float* __restrict__ b,    // [16]
    float* __restrict__ out)        // [64,16,252,252]
{
    __shared__ float lds[6][20][40];  // 19200 B

    const int tx  = threadIdx.x;
    const int ty  = threadIdx.y;
    const int tid = ty * 32 + tx;

    const int tileX = blockIdx.x << 5;   // 0..224
    const int tileY = blockIdx.y << 4;   // 0..240
    const int batch = blockIdx.z;

    const float* xb = x + (size_t)batch * 6 * 256 * 256;

    // ---- stage input tile: float4 chunks. 6*20*9 = 1080 ----
    for (int i = tid; i < 1080; i += 256) {
        int c   = i / 180;
        int rem = i - c * 180;
        int r   = rem / 9;
        int q   = rem - r * 9;
        int gr  = tileY + r;
        int gc0 = tileX + (q << 2);
        float4 v = make_float4(0.f, 0.f, 0.f, 0.f);
        if (gr < 256 && gc0 < 256)
            v = *reinterpret_cast<const float4*>(&xb[(c * 256 + gr) * 256 + gc0]);
        *reinterpret_cast<float4*>(&lds[c][r][q << 2]) = v;
    }
    __syncthreads();

    const int row0 = ty << 1;            // 0..14
    const int ocol = tileX + tx;
    float* ob = out + (size_t)batch * 16 * 252 * 252;
    const bool colok = (ocol < 252);
    const float* ldsBase = &lds[0][row0][tx];

    // ================= group 0 : out 0..7 =================
    {
        float acc[8][2];
        #pragma unroll
        for (int o = 0; o < 8; ++o) { float bv = b[o]; acc[o][0] = bv; acc[o][1] = bv; }

        run_group<26>(SCHED0, Wp, ldsBase, acc);

        if (colok) {
            #pragma unroll
            for (int o = 0; o < 8; ++o)
                #pragma unroll
                for (int dy = 0; dy < 2; ++dy) {
                    int orow = tileY + row0 + dy;
                    if (orow < 252) {
                        float z = acc[o][dy] * (2.0f / 3.0f);
                        float e = __expf(2.0f * z);
                        float rr = __builtin_amdgcn_rcpf(e + 1.0f);
                        ob[(o * 252 + orow) * 252 + ocol] = 1.7159f * (1.0f - 2.0f * rr);
                    }
                }
        }
    }

    __builtin_amdgcn_sched_barrier(0);

    // ================= group 1 : out 8..15 =================
    {
        float acc[8][2];
        #pragma unroll
        for (int o = 0; o < 8; ++o) { float bv = b[8 + o]; acc[o][0] = bv; acc[o][1] = bv; }

        run_group<34>(SCHED1, Wp, ldsBase, acc);

        if (colok) {
            #pragma unroll
            for (int o = 0; o < 8; ++o)
                #pragma unroll
                for (int dy = 0; dy < 2; ++dy) {
                    int orow = tileY + row0 + dy;
                    if (orow < 252) {
                        float z = acc[o][dy] * (2.0f / 3.0f);
                        float e = __expf(2.0f * z);
                        float rr = __builtin_amdgcn_rcpf(e + 1.0f);
                        ob[((8 + o) * 252 + orow) * 252 + ocol] = 1.7159f * (1.0f - 2.0f * rr);
                    }
                }
        }
    }
}

extern "C" void kernel_launch(void* const* d_in, const int* in_sizes, int n_in,
                              void* d_out, int out_size, void* d_ws, size_t ws_size,
                              hipStream_t stream) {
    const float* x = (const float*)d_in[0];
    const float* W = (const float*)d_in[1];
    const float* b = (const float*)d_in[2];
    float* out = (float*)d_out;
    float* Wp  = (float*)d_ws;     // needs 16*6*32*4 = 12288 B

    hipLaunchKernelGGL(prep_weights, dim3(12), dim3(256), 0, stream, W, Wp);

    dim3 grid(8, 16, 64);
    dim3 block(32, 8);
    hipLaunchKernelGGL(c3_partial_conv_kernel, grid, block, 0, stream, x, Wp, b, out);
}

// Round 8
// 252.069 us; speedup vs baseline: 1.5575x; 1.5575x over previous
//
#include <hip/hip_runtime.h>

// C3 partial conv: x[64,6,256,256] f32, W[16,6,5,5] f32 (sparse table), b[16].
// out[64,16,252,252] f32 = 1.7159*tanh((2/3)*(conv_valid + b)).
//
// Round 11: packed-fp32 attack. r10 (per-lane VMEM weights) pegged VALUBusy
// at 100 and regressed -> weights stay on the SCALAR path. r10's saturation
// calibrates VALUBusy: r7's 61% x 273us = ~6000 VALU instrs/thread, 2x the
// 3000-FMA minimum (register-parking moves). Wall = VALU instruction count.
// Fix: v_pk_fma_f32 via float2 ext-vector + __builtin_elementwise_fma.
// Row dot-products paired along kx: win row = {(kx0,kx1),(kx2,kx3),(kx4,0)},
// weight pairs s_loaded BEFORE the switch (branch-independent), even/odd
// packed partial sums, horizontal add per case. 50 FMA -> 30 pk-FMA per
// (o,c) case; ~2400 VALU/thread. Skeleton = r7 (2-row, 19.2KB LDS, rolled
// switch, ~5KB hot code, L1I-safe).
// NO launch_bounds min-waves arg (hard VGPR clamp -> scratch, r2/r4).

typedef float v2f __attribute__((ext_vector_type(2)));

__device__ __forceinline__ v2f mk2(float a, float b) { v2f r; r.x = a; r.y = b; return r; }

__device__ __forceinline__ void conv25pk(const v2f (&w)[5][3],
                                         const v2f (&win)[6][3],
                                         v2f& ap) {
    v2f tA = mk2(0.f, 0.f), tB = mk2(0.f, 0.f);
    #pragma unroll
    for (int ky = 0; ky < 5; ++ky)
        #pragma unroll
        for (int k = 0; k < 3; ++k) {
            tA = __builtin_elementwise_fma(win[ky][k],     w[ky][k], tA);  // row dy=0
            tB = __builtin_elementwise_fma(win[ky + 1][k], w[ky][k], tB);  // row dy=1
        }
    ap.x += tA.x + tA.y;
    ap.y += tB.x + tB.y;
}

__global__ __launch_bounds__(256) void c3_partial_conv_kernel(
    const float* __restrict__ x,   // [64,6,256,256]
    const float* __restrict__ W,   // [16,6,5,5]
    const float* __restrict__ b,   // [16]
    float* __restrict__ out)       // [64,16,252,252]
{
    constexpr int G0N[6] = {4, 5, 5, 5, 4, 3};
    constexpr int G0O[6][5] = {
        {0, 4, 5, 6, 0},
        {0, 1, 5, 6, 7},
        {0, 1, 2, 6, 7},
        {1, 2, 3, 6, 7},
        {2, 3, 4, 7, 0},
        {3, 4, 5, 0, 0}};
    constexpr int G1N[6] = {6, 5, 5, 5, 6, 7};
    constexpr int G1O[6][7] = {
        {9, 10, 11, 12, 14, 15, 8},
        {10, 11, 12, 13, 15, 8, 8},
        {8, 11, 13, 14, 15, 8, 8},
        {8, 9, 12, 14, 15, 8, 8},
        {8, 9, 10, 12, 13, 15, 8},
        {8, 9, 10, 11, 13, 14, 15}};

    __shared__ float lds[6][20][40];  // 19200 B

    const int tx  = threadIdx.x;
    const int ty  = threadIdx.y;
    const int tid = ty * 32 + tx;

    const int tileX = blockIdx.x << 5;   // 0..224
    const int tileY = blockIdx.y << 4;   // 0..240
    const int batch = blockIdx.z;

    const float* xb = x + (size_t)batch * 6 * 256 * 256;

    // ---- stage input tile: float4 chunks. 6*20*9 = 1080 ----
    for (int i = tid; i < 1080; i += 256) {
        int c   = i / 180;
        int rem = i - c * 180;
        int r   = rem / 9;
        int q   = rem - r * 9;
        int gr  = tileY + r;
        int gc0 = tileX + (q << 2);
        float4 v = make_float4(0.f, 0.f, 0.f, 0.f);
        if (gr < 256 && gc0 < 256)
            v = *reinterpret_cast<const float4*>(&xb[(c * 256 + gr) * 256 + gc0]);
        *reinterpret_cast<float4*>(&lds[c][r][q << 2]) = v;
    }
    __syncthreads();

    const int row0 = ty << 1;            // 0..14
    const int ocol = tileX + tx;
    float* ob = out + (size_t)batch * 16 * 252 * 252;
    const bool colok = (ocol < 252);
    const float* ldsBase = &lds[0][row0][tx];

    // ================= group 0 : out 0..7 =================
    {
        v2f accp[8];
        #pragma unroll
        for (int o = 0; o < 8; ++o) { float bv = b[o]; accp[o] = mk2(bv, bv); }

        #pragma unroll 1
        for (int c = 0; c < 6; ++c) {
            v2f win[6][3];
            const float* cb = ldsBase + c * 800;
            #pragma unroll
            for (int r = 0; r < 6; ++r) {
                const float* rb = cb + r * 40;
                win[r][0] = mk2(rb[0], rb[1]);
                win[r][1] = mk2(rb[2], rb[3]);
                win[r][2] = mk2(rb[4], 0.0f);   // pad lane multiplies by 0
            }

            const int n = G0N[c];
            #pragma unroll 1
            for (int oi = 0; oi < n; ++oi) {
                const int o = G0O[c][oi];
                const float* wp = W + (o * 6 + c) * 25;
                // weight pairs: uniform s_loads, issued BEFORE the branch
                v2f w[5][3];
                #pragma unroll
                for (int ky = 0; ky < 5; ++ky) {
                    w[ky][0] = mk2(wp[ky * 5 + 0], wp[ky * 5 + 1]);
                    w[ky][1] = mk2(wp[ky * 5 + 2], wp[ky * 5 + 3]);
                    w[ky][2] = mk2(wp[ky * 5 + 4], 0.0f);
                }
                switch (o) {                   // routes accumulator only
                    case 0: conv25pk(w, win, accp[0]); break;
                    case 1: conv25pk(w, win, accp[1]); break;
                    case 2: conv25pk(w, win, accp[2]); break;
                    case 3: conv25pk(w, win, accp[3]); break;
                    case 4: conv25pk(w, win, accp[4]); break;
                    case 5: conv25pk(w, win, accp[5]); break;
                    case 6: conv25pk(w, win, accp[6]); break;
                    case 7: conv25pk(w, win, accp[7]); break;
                    default: break;
                }
            }
        }

        if (colok) {
            #pragma unroll
            for (int o = 0; o < 8; ++o) {
                float av[2] = {accp[o].x, accp[o].y};
                #pragma unroll
                for (int dy = 0; dy < 2; ++dy) {
                    int orow = tileY + row0 + dy;
                    if (orow < 252) {
                        float z = av[dy] * (2.0f / 3.0f);
                        float e = __expf(2.0f * z);
                        float rr = __builtin_amdgcn_rcpf(e + 1.0f);
                        ob[(o * 252 + orow) * 252 + ocol] = 1.7159f * (1.0f - 2.0f * rr);
                    }
                }
            }
        }
    }

    __builtin_amdgcn_sched_barrier(0);

    // ================= group 1 : out 8..15 =================
    {
        v2f accp[8];
        #pragma unroll
        for (int o = 0; o < 8; ++o) { float bv = b[8 + o]; accp[o] = mk2(bv, bv); }

        #pragma unroll 1
        for (int c = 0; c < 6; ++c) {
            v2f win[6][3];
            const float* cb = ldsBase + c * 800;
            #pragma unroll
            for (int r = 0; r < 6; ++r) {
                const float* rb = cb + r * 40;
                win[r][0] = mk2(rb[0], rb[1]);
                win[r][1] = mk2(rb[2], rb[3]);
                win[r][2] = mk2(rb[4], 0.0f);
            }

            const int n = G1N[c];
            #pragma unroll 1
            for (int oi = 0; oi < n; ++oi) {
                const int o = G1O[c][oi];
                const float* wp = W + (o * 6 + c) * 25;
                v2f w[5][3];
                #pragma unroll
                for (int ky = 0; ky < 5; ++ky) {
                    w[ky][0] = mk2(wp[ky * 5 + 0], wp[ky * 5 + 1]);
                    w[ky][1] = mk2(wp[ky * 5 + 2], wp[ky * 5 + 3]);
                    w[ky][2] = mk2(wp[ky * 5 + 4], 0.0f);
                }
                switch (o) {
                    case  8: conv25pk(w, win, accp[0]); break;
                    case  9: conv25pk(w, win, accp[1]); break;
                    case 10: conv25pk(w, win, accp[2]); break;
                    case 11: conv25pk(w, win, accp[3]); break;
                    case 12: conv25pk(w, win, accp[4]); break;
                    case 13: conv25pk(w, win, accp[5]); break;
                    case 14: conv25pk(w, win, accp[6]); break;
                    case 15: conv25pk(w, win, accp[7]); break;
                    default: break;
                }
            }
        }

        if (colok) {
            #pragma unroll
            for (int o = 0; o < 8; ++o) {
                float av[2] = {accp[o].x, accp[o].y};
                #pragma unroll
                for (int dy = 0; dy < 2; ++dy) {
                    int orow = tileY + row0 + dy;
                    if (orow < 252) {
                        float z = av[dy] * (2.0f / 3.0f);
                        float e = __expf(2.0f * z);
                        float rr = __builtin_amdgcn_rcpf(e + 1.0f);
                        ob[((8 + o) * 252 + orow) * 252 + ocol] = 1.7159f * (1.0f - 2.0f * rr);
                    }
                }
            }
        }
    }
}

extern "C" void kernel_launch(void* const* d_in, const int* in_sizes, int n_in,
                              void* d_out, int out_size, void* d_ws, size_t ws_size,
                              hipStream_t stream) {
    const float* x = (const float*)d_in[0];
    const float* W = (const float*)d_in[1];
    const float* b = (const float*)d_in[2];
    float* out = (float*)d_out;

    dim3 grid(8, 16, 64);
    dim3 block(32, 8);
    hipLaunchKernelGGL(c3_partial_conv_kernel, grid, block, 0, stream, x, W, b, out);
}